// Round 9
// baseline (104.574 us; speedup 1.0000x reference)
//
#include <hip/hip_runtime.h>

#define COLS 8192

// lgkmcnt-only barrier (1 wave/block: s_barrier is trivial; the waitcnt
// guarantees LDS write->read visibility without draining global stores).
__device__ __forceinline__ void bar_lds() {
    asm volatile("s_waitcnt lgkmcnt(0)" ::: "memory");
    __builtin_amdgcn_sched_barrier(0);
    __builtin_amdgcn_s_barrier();
    __builtin_amdgcn_sched_barrier(0);
}

// analysis: d[i]=h3*a[2i]-h2*a[2i-1]+h1*a[2i-2]-h0*a[2i-3]; a'[i]=h·a[2i-m]
#define ANA_LEVEL(CIN, ain, aout, dout, F0, F1, F2, F3)                       \
    {                                                                         \
        const int _src = (l - 1) & 63;                                        \
        const float _m1 = __shfl(ain[(CIN)-1], _src);                         \
        const float _m2 = __shfl(ain[(CIN)-2], _src);                         \
        const float _m3 = __shfl(ain[(CIN)-3], _src);                         \
        dout[0] = (F3)*ain[0] - (F2)*_m1 + (F1)*_m2 - (F0)*_m3;               \
        aout[0] = (F0)*ain[0] + (F1)*_m1 + (F2)*_m2 + (F3)*_m3;               \
        dout[1] = (F3)*ain[2] - (F2)*ain[1] + (F1)*ain[0] - (F0)*_m1;         \
        aout[1] = (F0)*ain[2] + (F1)*ain[1] + (F2)*ain[0] + (F3)*_m1;         \
        _Pragma("unroll")                                                     \
        for (int _j = 2; _j < (CIN)/2; ++_j) {                                \
            dout[_j] = (F3)*ain[2*_j] - (F2)*ain[2*_j-1] + (F1)*ain[2*_j-2] - (F0)*ain[2*_j-3]; \
            aout[_j] = (F0)*ain[2*_j] + (F1)*ain[2*_j-1] + (F2)*ain[2*_j-2] + (F3)*ain[2*_j-3]; \
        }                                                                     \
    }

// synthesis: rec[2j]=h3*d[j]+h1*d[j+1]+h0*a[j]+h2*a[j+1];
//            rec[2j+1]=-h2*d[j+1]-h0*d[j+2]+h1*a[j+1]+h3*a[j+2]
#define SYN_LEVEL(CD, din, ain, rout, F0, F1, F2, F3)                         \
    {                                                                         \
        const int _src = (l + 1) & 63;                                        \
        const float _d0 = __shfl(din[0], _src);                               \
        const float _d1 = __shfl(din[1], _src);                               \
        const float _a0 = __shfl(ain[0], _src);                               \
        const float _a1 = __shfl(ain[1], _src);                               \
        _Pragma("unroll")                                                     \
        for (int _j = 0; _j < (CD); ++_j) {                                   \
            const float dj  = din[_j];                                        \
            const float dj1 = (_j+1 < (CD)) ? din[_j+1] : _d0;                \
            const float dj2 = (_j+2 < (CD)) ? din[_j+2] : ((_j+1 < (CD)) ? _d0 : _d1); \
            const float aj  = ain[_j];                                        \
            const float aj1 = (_j+1 < (CD)) ? ain[_j+1] : _a0;                \
            const float aj2 = (_j+2 < (CD)) ? ain[_j+2] : ((_j+1 < (CD)) ? _a0 : _a1); \
            rout[2*_j]   = (F3)*dj + (F1)*dj1 + (F0)*aj + (F2)*aj1;           \
            rout[2*_j+1] = -(F2)*dj1 - (F0)*dj2 + (F1)*aj1 + (F3)*aj2;        \
        }                                                                     \
    }

// One WAVE per row. No block barriers anywhere: wide levels in registers
// (lane-blocked, __shfl halos), levels 5..7 in tiny LDS (single-wave order).
__global__ __launch_bounds__(64) void despawn_wave(
    const float* __restrict__ x, const float* __restrict__ scaling,
    float* __restrict__ out, int rows)
{
    __shared__ float T[256];                  // a4
    __shared__ float D5[128], A5[128];
    __shared__ float D6[64],  A6[64];
    __shared__ float D7[32],  AP[32];
    __shared__ float R7[64],  R6[128], R5[256];

    const int row = blockIdx.x;
    const int l   = threadIdx.x;              // 0..63

    const float* __restrict__ xg = x + (size_t)row * COLS;
    float* __restrict__ out_rec  = out + (size_t)row * COLS;
    float* __restrict__ out_coef = out + (size_t)rows * COLS + (size_t)row * COLS;

    float h[32];
#pragma unroll
    for (int q = 0; q < 32; ++q) h[q] = scaling[q];   // uniform -> scalar loads

    // ---------------- analysis lev0: x -> d0(global), a0(64 regs) ----------
    float a0[64];
    {
        const float F0=h[0], F1=h[1], F2=h[2], F3=h[3];
        const float4* __restrict__ xg4 = reinterpret_cast<const float4*>(xg);
        float4* __restrict__ o4 = reinterpret_cast<float4*>(out_coef) + 16*l;
        float4 prev = xg4[(32*l - 1) & 2047];          // x[128l-4..128l-1]
        #pragma unroll
        for (int q = 0; q < 32; q += 2) {
            float4 cur = xg4[32*l + q];
            float4 dv;
            dv.x      = F3*cur.x - F2*prev.w + F1*prev.z - F0*prev.y;
            a0[2*q]   = F0*cur.x + F1*prev.w + F2*prev.z + F3*prev.y;
            dv.y      = F3*cur.z - F2*cur.y + F1*cur.x - F0*prev.w;
            a0[2*q+1] = F0*cur.z + F1*cur.y + F2*cur.x + F3*prev.w;
            prev = cur;
            cur = xg4[32*l + q + 1];
            dv.z      = F3*cur.x - F2*prev.w + F1*prev.z - F0*prev.y;
            a0[2*q+2] = F0*cur.x + F1*prev.w + F2*prev.z + F3*prev.y;
            dv.w      = F3*cur.z - F2*cur.y + F1*cur.x - F0*prev.w;
            a0[2*q+3] = F0*cur.z + F1*cur.y + F2*cur.x + F3*prev.w;
            prev = cur;
            o4[q/2] = dv;
        }
    }

    // ---------------- analysis lev1: a0 -> d1(global), a1(32) --------------
    float a1[32];
    {
        float d1v[32];
        ANA_LEVEL(64, a0, a1, d1v, h[4], h[5], h[6], h[7]);
        float4* __restrict__ o4 = reinterpret_cast<float4*>(out_coef + 4096) + 8*l;
        #pragma unroll
        for (int j = 0; j < 8; ++j)
            o4[j] = make_float4(d1v[4*j], d1v[4*j+1], d1v[4*j+2], d1v[4*j+3]);
    }

    // ---------------- analysis lev2..4: keep d2,d3,d4 in regs --------------
    float a2[16], d2[16];
    ANA_LEVEL(32, a1, a2, d2, h[8], h[9], h[10], h[11]);
    {
        float4* __restrict__ o4 = reinterpret_cast<float4*>(out_coef + 6144) + 4*l;
        #pragma unroll
        for (int j = 0; j < 4; ++j)
            o4[j] = make_float4(d2[4*j], d2[4*j+1], d2[4*j+2], d2[4*j+3]);
    }
    float a3[8], d3[8];
    ANA_LEVEL(16, a2, a3, d3, h[12], h[13], h[14], h[15]);
    {
        float4* __restrict__ o4 = reinterpret_cast<float4*>(out_coef + 7168) + 2*l;
        o4[0] = make_float4(d3[0], d3[1], d3[2], d3[3]);
        o4[1] = make_float4(d3[4], d3[5], d3[6], d3[7]);
    }
    float a4[4], d4[4];
    ANA_LEVEL(8, a3, a4, d4, h[16], h[17], h[18], h[19]);
    reinterpret_cast<float4*>(out_coef + 7680)[l] = make_float4(d4[0], d4[1], d4[2], d4[3]);

    // ---------------- LDS tail: lev5..7 analysis + synth 7..5 --------------
    #pragma unroll
    for (int q = 0; q < 4; ++q) T[4*l + q] = a4[q];
    bar_lds();
    {   // lev5: T(256) -> D5,A5(128)
        const float F0=h[20],F1=h[21],F2=h[22],F3=h[23];
        #pragma unroll
        for (int u = 0; u < 2; ++u) {
            const int i = l + 64*u, b = 2*i;
            const float x0=T[b], x1=T[(b-1)&255], x2=T[(b-2)&255], x3=T[(b-3)&255];
            const float d = F3*x0 - F2*x1 + F1*x2 - F0*x3;
            D5[i] = d; A5[i] = F0*x0 + F1*x1 + F2*x2 + F3*x3;
            out_coef[7936 + i] = d;
        }
    }
    bar_lds();
    {   // lev6: A5(128) -> D6,A6(64)
        const float F0=h[24],F1=h[25],F2=h[26],F3=h[27];
        const int b = 2*l;
        const float x0=A5[b], x1=A5[(b-1)&127], x2=A5[(b-2)&127], x3=A5[(b-3)&127];
        const float d = F3*x0 - F2*x1 + F1*x2 - F0*x3;
        D6[l] = d; A6[l] = F0*x0 + F1*x1 + F2*x2 + F3*x3;
        out_coef[8064 + l] = d;
    }
    bar_lds();
    {   // lev7: A6(64) -> D7,AP(32)
        const float F0=h[28],F1=h[29],F2=h[30],F3=h[31];
        if (l < 32) {
            const int b = 2*l;
            const float x0=A6[b], x1=A6[(b-1)&63], x2=A6[(b-2)&63], x3=A6[(b-3)&63];
            const float d = F3*x0 - F2*x1 + F1*x2 - F0*x3;
            const float a = F0*x0 + F1*x1 + F2*x2 + F3*x3;
            D7[l] = d; AP[l] = a;
            out_coef[8128 + l] = d; out_coef[8160 + l] = a;
        }
    }
    bar_lds();
    {   // synth7 -> R7(64)
        const float F0=h[28],F1=h[29],F2=h[30],F3=h[31];
        if (l < 32) {
            const int j = l;
            const float dj=D7[j], dj1=D7[(j+1)&31], dj2=D7[(j+2)&31];
            const float aj=AP[j], aj1=AP[(j+1)&31], aj2=AP[(j+2)&31];
            R7[2*j]   = F3*dj + F1*dj1 + F0*aj + F2*aj1;
            R7[2*j+1] = -F2*dj1 - F0*dj2 + F1*aj1 + F3*aj2;
        }
    }
    bar_lds();
    {   // synth6 -> R6(128)
        const float F0=h[24],F1=h[25],F2=h[26],F3=h[27];
        const int j = l;
        const float dj=D6[j], dj1=D6[(j+1)&63], dj2=D6[(j+2)&63];
        const float aj=R7[j], aj1=R7[(j+1)&63], aj2=R7[(j+2)&63];
        R6[2*j]   = F3*dj + F1*dj1 + F0*aj + F2*aj1;
        R6[2*j+1] = -F2*dj1 - F0*dj2 + F1*aj1 + F3*aj2;
    }
    bar_lds();
    {   // synth5 -> R5(256)
        const float F0=h[20],F1=h[21],F2=h[22],F3=h[23];
        #pragma unroll
        for (int u = 0; u < 2; ++u) {
            const int j = l + 64*u;
            const float dj=D5[j], dj1=D5[(j+1)&127], dj2=D5[(j+2)&127];
            const float aj=R6[j], aj1=R6[(j+1)&127], aj2=R6[(j+2)&127];
            R5[2*j]   = F3*dj + F1*dj1 + F0*aj + F2*aj1;
            R5[2*j+1] = -F2*dj1 - F0*dj2 + F1*aj1 + F3*aj2;
        }
    }
    bar_lds();
    float r5[4];
    #pragma unroll
    for (int q = 0; q < 4; ++q) r5[q] = R5[4*l + q];

    // ---------------- synth lev4..2 (registers) ----------------------------
    float r4[8];
    SYN_LEVEL(4, d4, r5, r4, h[16], h[17], h[18], h[19]);
    float r3[16];
    SYN_LEVEL(8, d3, r4, r3, h[12], h[13], h[14], h[15]);
    float r2[32];
    SYN_LEVEL(16, d2, r3, r2, h[8], h[9], h[10], h[11]);

    // ---------------- synth lev1: d1 re-read (L2-hot) + r2 -> r1(64) -------
    float r1[64];
    {
        const float F0=h[4],F1=h[5],F2=h[6],F3=h[7];
        float dv[34];
        const float4* __restrict__ g4 = reinterpret_cast<const float4*>(out_coef + 4096);
        #pragma unroll
        for (int q = 0; q < 8; ++q) {
            const float4 v = g4[8*l + q];
            dv[4*q]=v.x; dv[4*q+1]=v.y; dv[4*q+2]=v.z; dv[4*q+3]=v.w;
        }
        const float2 he = *reinterpret_cast<const float2*>(out_coef + 4096 + ((32*l + 32) & 2047));
        dv[32]=he.x; dv[33]=he.y;
        const int src = (l + 1) & 63;
        const float a0h = __shfl(r2[0], src);
        const float a1h = __shfl(r2[1], src);
        #pragma unroll
        for (int j = 0; j < 32; ++j) {
            const float aj  = r2[j];
            const float aj1 = (j < 31) ? r2[j+1] : a0h;
            const float aj2 = (j < 30) ? r2[j+2] : ((j == 30) ? a0h : a1h);
            r1[2*j]   = F3*dv[j] + F1*dv[j+1] + F0*aj + F2*aj1;
            r1[2*j+1] = -F2*dv[j+1] - F0*dv[j+2] + F1*aj1 + F3*aj2;
        }
    }

    // ---------------- synth lev0: d0 re-read + r1 -> rec (streamed) --------
    {
        const float F0=h[0],F1=h[1],F2=h[2],F3=h[3];
        const float4* __restrict__ g4 = reinterpret_cast<const float4*>(out_coef);
        float4* __restrict__ o4 = reinterpret_cast<float4*>(out_rec) + 32*l;
        const int src = (l + 1) & 63;
        const float a0h = __shfl(r1[0], src);
        const float a1h = __shfl(r1[1], src);
        const float2 dhe = *reinterpret_cast<const float2*>(out_coef + ((64*l + 64) & 4095));
        float4 cur = g4[16*l];
        #pragma unroll
        for (int c = 0; c < 16; ++c) {
            float4 nf;
            if (c < 15) nf = g4[16*l + c + 1];
            else        nf = make_float4(dhe.x, dhe.y, 0.f, 0.f);
            float rr[8];
            #pragma unroll
            for (int t = 0; t < 4; ++t) {
                const int j = 4*c + t;
                const float dj  = (t==0)?cur.x:((t==1)?cur.y:((t==2)?cur.z:cur.w));
                const float dj1 = (t==0)?cur.y:((t==1)?cur.z:((t==2)?cur.w:nf.x));
                const float dj2 = (t==0)?cur.z:((t==1)?cur.w:((t==2)?nf.x:nf.y));
                const float aj  = r1[j];
                const float aj1 = (j < 63) ? r1[j+1] : a0h;
                const float aj2 = (j < 62) ? r1[j+2] : ((j == 62) ? a0h : a1h);
                rr[2*t]   = F3*dj + F1*dj1 + F0*aj + F2*aj1;
                rr[2*t+1] = -F2*dj1 - F0*dj2 + F1*aj1 + F3*aj2;
            }
            o4[2*c]   = make_float4(rr[0], rr[1], rr[2], rr[3]);
            o4[2*c+1] = make_float4(rr[4], rr[5], rr[6], rr[7]);
            cur = nf;
        }
    }
}

extern "C" void kernel_launch(void* const* d_in, const int* in_sizes, int n_in,
                              void* d_out, int out_size, void* d_ws, size_t ws_size,
                              hipStream_t stream) {
    const float* x       = (const float*)d_in[0];
    const float* scaling = (const float*)d_in[1];
    float* out           = (float*)d_out;
    const int rows = in_sizes[0] / COLS;
    despawn_wave<<<rows, 64, 0, stream>>>(x, scaling, out, rows);
}

// Round 10
// 42.731 us; speedup vs baseline: 2.4473x; 2.4473x over previous
//
#include <hip/hip_runtime.h>

#define COLS   8192
#define LEVELS 8
#define TPB    512

// LDS-only barrier: waits LDS ops, lets global (vmcnt) stores stay in flight
// across the phase chain. Full __syncthreads() is used once, after the wave-0
// tail, to drain coeff stores before synthesis re-reads them from global.
__device__ __forceinline__ void bar_lds() {
    asm volatile("s_waitcnt lgkmcnt(0)" ::: "memory");
    __builtin_amdgcn_sched_barrier(0);
    __builtin_amdgcn_s_barrier();
    __builtin_amdgcn_sched_barrier(0);
}

// One block per row.
// LDS: B(16K) + C(8K) approx ping-pong, D(8K) = details lev2..7 + final approx.
// __launch_bounds__(512, 8): forces VGPR<=64 so 4 blocks (32 waves) fit per CU
// (at the natural 68 VGPR the HW halves residency to 16 waves/CU — m69).
__global__ __launch_bounds__(TPB, 8) void despawn_kernel(
    const float* __restrict__ x, const float* __restrict__ scaling,
    float* __restrict__ out, int rows)
{
    __shared__ __align__(16) float B[COLS / 2];   // 16 KB
    __shared__ __align__(16) float C[COLS / 4];   // 8 KB
    __shared__ __align__(16) float D[COLS / 4];   // 8 KB
    __shared__ float filt[LEVELS * 4];

    const int row = blockIdx.x;
    const int tid = threadIdx.x;

    if (tid < LEVELS * 4) filt[tid] = scaling[tid];
    bar_lds();

    const float* __restrict__ xg       = x + (size_t)row * COLS;
    float* __restrict__       out_rec  = out + (size_t)row * COLS;
    float* __restrict__       out_coef = out + (size_t)rows * COLS + (size_t)row * COLS;

    // ---------------- analysis level 0 (global float4, 4 outputs/thread) ----
    // d[k] = g0*x[2k] + g1*x[2k-1] + g2*x[2k-2] + g3*x[2k-3]   (mod 8192)
    {
        const float h0 = filt[0], h1 = filt[1], h2 = filt[2], h3 = filt[3];
        const float g0 = h3, g1 = -h2, g2 = h1, g3 = -h0;
        const float4* __restrict__ xg4 = reinterpret_cast<const float4*>(xg);
        const int q8 = COLS / 8, qm = COLS / 4 - 1;
        for (int i = tid; i < q8; i += TPB) {
            const float4 va = xg4[(2 * i - 1) & qm];   // x[8i-4..8i-1]
            const float4 vb = xg4[2 * i];              // x[8i  ..8i+3]
            const float4 vc = xg4[2 * i + 1];          // x[8i+4..8i+7]
            float4 dv, av;
            dv.x = g0*vb.x + g1*va.w + g2*va.z + g3*va.y;
            av.x = h0*vb.x + h1*va.w + h2*va.z + h3*va.y;
            dv.y = g0*vb.z + g1*vb.y + g2*vb.x + g3*va.w;
            av.y = h0*vb.z + h1*vb.y + h2*vb.x + h3*va.w;
            dv.z = g0*vc.x + g1*vb.w + g2*vb.z + g3*vb.y;
            av.z = h0*vc.x + h1*vb.w + h2*vb.z + h3*vb.y;
            dv.w = g0*vc.z + g1*vc.y + g2*vc.x + g3*vb.w;
            av.w = h0*vc.z + h1*vc.y + h2*vc.x + h3*vb.w;
            reinterpret_cast<float4*>(out_coef)[i] = dv;   // stays in flight
            reinterpret_cast<float4*>(B)[i]        = av;
        }
        bar_lds();
    }

    // ---------------- analysis levels 1..3 (LDS float4, 4 outputs/thread) ---
    int n = COLS / 2, coff = COLS / 2, dOff = 0;
    float* cur = B;
    float* nxt = C;
    for (int lev = 1; lev <= 3; ++lev) {
        const float h0 = filt[4*lev+0], h1 = filt[4*lev+1],
                    h2 = filt[4*lev+2], h3 = filt[4*lev+3];
        const float g0 = h3, g1 = -h2, g2 = h1, g3 = -h0;
        const int half = n >> 1, qq = half >> 2, qm = (n >> 2) - 1;
        const float4* c4 = reinterpret_cast<const float4*>(cur);
        float4* o4 = reinterpret_cast<float4*>(out_coef + coff);
        float4* n4 = reinterpret_cast<float4*>(nxt);
        float4* D4 = reinterpret_cast<float4*>(D + dOff);
        const bool toD = (lev >= 2);
        for (int p = tid; p < qq; p += TPB) {
            const float4 va = c4[(2 * p - 1) & qm];
            const float4 vb = c4[2 * p];
            const float4 vc = c4[2 * p + 1];
            float4 dv, av;
            dv.x = g0*vb.x + g1*va.w + g2*va.z + g3*va.y;
            av.x = h0*vb.x + h1*va.w + h2*va.z + h3*va.y;
            dv.y = g0*vb.z + g1*vb.y + g2*vb.x + g3*va.w;
            av.y = h0*vb.z + h1*vb.y + h2*vb.x + h3*va.w;
            dv.z = g0*vc.x + g1*vb.w + g2*vb.z + g3*vb.y;
            av.z = h0*vc.x + h1*vb.w + h2*vb.z + h3*vb.y;
            dv.w = g0*vc.z + g1*vc.y + g2*vc.x + g3*vb.w;
            av.w = h0*vc.z + h1*vc.y + h2*vc.x + h3*vb.w;
            o4[p] = dv;            // stays in flight
            n4[p] = av;
            if (toD) D4[p] = dv;
        }
        bar_lds();
        coff += half;
        if (toD) dOff += half;
        n = half;
        float* t = cur; cur = nxt; nxt = t;
    }
    // approx(512) now in C (cur == C)

    // ---------------- wave-0 tail: levels 4..7 both directions --------------
    // D layout: lev2@0(1024) lev3@1024(512) lev4@1536(256) lev5@1792(128)
    //           lev6@1920(64) lev7@1984(32) approx@2016(32)
    if (tid < 64) {
        float* acur = C;
        float* anxt = B;
        int nn = 512, coffW = 7680, dW = 1536;
        for (int lev = 4; lev <= 7; ++lev) {
            const float h0 = filt[4*lev+0], h1 = filt[4*lev+1],
                        h2 = filt[4*lev+2], h3 = filt[4*lev+3];
            const float g0 = h3, g1 = -h2, g2 = h1, g3 = -h0;
            const int half = nn >> 1, mask = nn - 1;
            for (int i = tid; i < half; i += 64) {
                const int b = 2 * i;
                const float x0 = acur[b];
                const float x1 = acur[(b - 1) & mask];
                const float x2 = acur[(b - 2) & mask];
                const float x3 = acur[(b - 3) & mask];
                const float d = g0*x0 + g1*x1 + g2*x2 + g3*x3;
                const float a = h0*x0 + h1*x1 + h2*x2 + h3*x3;
                D[dW + i] = d;
                out_coef[coffW + i] = d;
                if (lev == 7) { D[2016 + i] = a; out_coef[8160 + i] = a; }
                else          anxt[i] = a;
            }
            __builtin_amdgcn_wave_barrier();
            coffW += half; dW += half; nn = half;
            float* t = acur; acur = anxt; anxt = t;
        }
        // synthesis lev7..4 (in-wave)
        int mS = 32, dS = 1984;
        const float* aprevW = D + 2016;
        for (int lev = 7; lev >= 4; --lev) {
            const float h0 = filt[4*lev+0], h1 = filt[4*lev+1],
                        h2 = filt[4*lev+2], h3 = filt[4*lev+3];
            const float g0 = h3, g1 = -h2, g2 = h1, g3 = -h0;
            const int mm = mS - 1;
            float* recW = (lev & 1) ? B : C;
            for (int j = tid; j < mS; j += 64) {
                const float dj  = D[dS + j];
                const float dj1 = D[dS + ((j + 1) & mm)];
                const float dj2 = D[dS + ((j + 2) & mm)];
                const float aj  = aprevW[j];
                const float aj1 = aprevW[(j + 1) & mm];
                const float aj2 = aprevW[(j + 2) & mm];
                recW[2*j]     = g0*dj  + g2*dj1 + h0*aj  + h2*aj1;
                recW[2*j + 1] = g1*dj1 + g3*dj2 + h1*aj1 + h3*aj2;
            }
            __builtin_amdgcn_wave_barrier();
            aprevW = recW; mS <<= 1; dS -= mS;
        }
    }
    __syncthreads();   // FULL drain: coeff stores must be visible before re-read
    // lev4 rec (512) now in C

    // ---------------- synthesis levels 3..0 (all threads, 4 out/thread) -----
    // rec[2j]   = g0*d[j]   + g2*d[j+1] + h0*a[j]   + h2*a[j+1]
    // rec[2j+1] = g1*d[j+1] + g3*d[j+2] + h1*a[j+1] + h3*a[j+2]   (mod m)
#define SYNTH_BODY(d2)                                                        \
    for (int p = tid; p < mp; p += TPB) {                                     \
        const float2 dv0 = (d2)[p];                                           \
        const float2 dv1 = (d2)[(p + 1) & mm];                                \
        const float2 av0 = a2[p];                                             \
        const float2 av1 = a2[(p + 1) & mm];                                  \
        const float r0 = g0*dv0.x + g2*dv0.y + h0*av0.x + h2*av0.y;           \
        const float r1 = g1*dv0.y + g3*dv1.x + h1*av0.y + h3*av1.x;           \
        const float r2 = g0*dv0.y + g2*dv1.x + h0*av0.y + h2*av1.x;           \
        const float r3 = g1*dv1.x + g3*dv1.y + h1*av1.x + h3*av1.y;           \
        const float4 rv = make_float4(r0, r1, r2, r3);                        \
        if (last) reinterpret_cast<float4*>(out_rec)[p] = rv;                 \
        else      reinterpret_cast<float4*>(rec)[p]     = rv;                 \
    }

    const float* aprev = C;
    int m = 512;
    for (int lev = 3; lev >= 0; --lev) {
        const float h0 = filt[4*lev+0], h1 = filt[4*lev+1],
                    h2 = filt[4*lev+2], h3 = filt[4*lev+3];
        const float g0 = h3, g1 = -h2, g2 = h1, g3 = -h0;
        const int mp = m >> 1, mm = mp - 1;
        const float2* a2 = reinterpret_cast<const float2*>(aprev);
        float* rec = (lev & 1) ? B : C;   // lev3->B lev2->C lev1->B
        const bool last = (lev == 0);
        if (lev >= 2) {
            const float2* dL = reinterpret_cast<const float2*>(D + ((lev == 3) ? 1024 : 0));
            SYNTH_BODY(dL)
        } else {
            const float2* __restrict__ dG =
                reinterpret_cast<const float2*>(out_coef + ((lev == 1) ? 4096 : 0));
            SYNTH_BODY(dG)
        }
        if (lev) bar_lds();
        aprev = rec; m <<= 1;
    }
#undef SYNTH_BODY
}

extern "C" void kernel_launch(void* const* d_in, const int* in_sizes, int n_in,
                              void* d_out, int out_size, void* d_ws, size_t ws_size,
                              hipStream_t stream) {
    const float* x       = (const float*)d_in[0];
    const float* scaling = (const float*)d_in[1];
    float* out           = (float*)d_out;
    const int rows = in_sizes[0] / COLS;
    despawn_kernel<<<rows, TPB, 0, stream>>>(x, scaling, out, rows);
}